// Round 5
// baseline (158.578 us; speedup 1.0000x reference)
//
#include <hip/hip_runtime.h>
#include <hip/hip_bf16.h>

// Problem constants
#define BDIM 8
#define HDIM 64
#define WDIM 64
#define CDIM 192
#define CIDIM 384
#define MTOK (BDIM * HDIM * WDIM)   // 32768 tokens

using bf16 = __hip_bfloat16;
typedef __attribute__((ext_vector_type(8))) short short8;   // 8 bf16 (4 VGPRs)
typedef __attribute__((ext_vector_type(4))) float f32x4;

__device__ __forceinline__ float silu_f(float v) { return v / (1.0f + __expf(-v)); }
__device__ __forceinline__ float bf2f(short s) {
    union { unsigned u; float f; } x; x.u = ((unsigned)(unsigned short)s) << 16; return x.f;
}

// async global->LDS, 16B per lane. LDS dest must be WAVE-UNIFORM base (+lane*16);
// the GLOBAL source address is per-lane.
__device__ __forceinline__ void gload_lds16(const bf16* g, bf16* l) {
    __builtin_amdgcn_global_load_lds(
        (const __attribute__((address_space(1))) void*)g,
        (__attribute__((address_space(3))) void*)l, 16, 0, 0);
}

// ---------------------------------------------------------------------------
// MFMA GEMM: C[M,N] = A[M,K] @ B[K,N], A bf16 [M,K], B TRANSPOSED bf16 [N,K].
// BM=128, BN=64, BK=64. 256 threads = 4 waves 2x2; wave tile 64x32 (4x2 frags).
// LDS linear, 16B slots XOR-swizzled both-sides.
// EPI: 0 = bf16; 1 = +resid -> fp32+bf16; 2 = silu(+bias) -> bf16; 3 = +bias+resid -> fp32
// ---------------------------------------------------------------------------
template <int EPI>
__launch_bounds__(256, 4)
__global__ void gemm_mfma(const bf16* __restrict__ A, const bf16* __restrict__ BT,
                          const float* __restrict__ bias, const float* __restrict__ resid,
                          float* __restrict__ outF, bf16* __restrict__ outB,
                          int M, int N, int K)
{
    __shared__ bf16 As[128 * 64];
    __shared__ bf16 Bs[64 * 64];

    const int tid  = threadIdx.x;
    const int lane = tid & 63;
    const int wv   = tid >> 6;
    const int wm   = wv >> 1;
    const int wn   = wv & 1;
    const int m0   = blockIdx.y * 128;
    const int n0   = blockIdx.x * 64;

    const int srow  = lane >> 3;
    const int sslot = lane & 7;

    f32x4 acc[4][2] = {};

    for (int k0 = 0; k0 < K; k0 += 64) {
        #pragma unroll
        for (int i = 0; i < 4; ++i) {
            const int rb = wv * 32 + i * 8;
            const int r  = rb + srow;
            gload_lds16(A + (size_t)(m0 + r) * K + k0 + ((sslot ^ (r & 7)) << 3),
                        &As[rb * 64]);
        }
        #pragma unroll
        for (int i = 0; i < 2; ++i) {
            const int rb = wv * 16 + i * 8;
            const int r  = rb + srow;
            gload_lds16(BT + (size_t)(n0 + r) * K + k0 + ((sslot ^ (r & 7)) << 3),
                        &Bs[rb * 64]);
        }
        __syncthreads();

        #pragma unroll
        for (int kk = 0; kk < 2; ++kk) {
            const int t = kk * 4 + (lane >> 4);
            short8 af[4], bfr[2];
            #pragma unroll
            for (int mi = 0; mi < 4; ++mi) {
                const int m = wm * 64 + mi * 16 + (lane & 15);
                af[mi] = *reinterpret_cast<const short8*>(&As[m * 64 + ((t ^ (m & 7)) << 3)]);
            }
            #pragma unroll
            for (int ni = 0; ni < 2; ++ni) {
                const int n = wn * 32 + ni * 16 + (lane & 15);
                bfr[ni] = *reinterpret_cast<const short8*>(&Bs[n * 64 + ((t ^ (n & 7)) << 3)]);
            }
            #pragma unroll
            for (int mi = 0; mi < 4; ++mi)
                #pragma unroll
                for (int ni = 0; ni < 2; ++ni)
                    acc[mi][ni] = __builtin_amdgcn_mfma_f32_16x16x32_bf16(
                        af[mi], bfr[ni], acc[mi][ni], 0, 0, 0);
        }
        __syncthreads();
    }

    const int colb = n0 + wn * 32 + (lane & 15);
    const int rowb = m0 + wm * 64 + (lane >> 4) * 4;
    #pragma unroll
    for (int mi = 0; mi < 4; ++mi) {
        #pragma unroll
        for (int ni = 0; ni < 2; ++ni) {
            const int c = colb + ni * 16;
            #pragma unroll
            for (int j = 0; j < 4; ++j) {
                const int row = rowb + mi * 16 + j;
                const size_t off = (size_t)row * N + c;
                const float v = acc[mi][ni][j];
                if constexpr (EPI == 0) {
                    outB[off] = __float2bfloat16(v);
                } else if constexpr (EPI == 1) {
                    const float r = v + resid[off];
                    outF[off] = r;
                    outB[off] = __float2bfloat16(r);
                } else if constexpr (EPI == 2) {
                    outB[off] = __float2bfloat16(silu_f(v + bias[c]));
                } else {
                    outF[off] = v + bias[c] + resid[off];
                }
            }
        }
    }
}

// ---------------------------------------------------------------------------
// Depthwise 3x3 conv + bias + silu, x4 scan-merge, gate silu(z).  v5:
// block = one image row (64 px) x 96-ch quarter. Stage rows h-1,h,h+1 into
// LDS [3][64][96] bf16 (36 KB) via global_load_lds (per-lane global src,
// linear LDS dest). Compute: item f = px*12+cg -> wave lanes read CONTIGUOUS
// LDS (conflict-free ds_read_b128). 256 thr x 3 items of (8ch x 1px).
// Grid: 512 rows x 4 quarters = 2048 blocks.
// ---------------------------------------------------------------------------
#define QCH 96
__launch_bounds__(256)
__global__ void dwconv_gate_v5(const bf16* __restrict__ xz, const float* __restrict__ wT,
                               const float* __restrict__ conv_b, bf16* __restrict__ y)
{
    __shared__ bf16 lx[3 * 64 * QCH];   // [row][pix][96], 36864 B

    const int blk   = blockIdx.x;
    const int q     = blk & 3;           // channel quarter
    const int rowid = blk >> 2;          // b*64 + h
    const int h     = rowid & 63;
    const int tid   = threadIdx.x;
    const int wv    = tid >> 6;
    const int lane  = tid & 63;
    const int qc0   = q * QCH;

    // --- stage 3 rows (clamped): 36 instrs total, 9 per wave ---
    #pragma unroll
    for (int i = 0; i < 9; ++i) {
        const int g   = wv * 9 + i;       // 0..35
        const int row = g / 12;           // 0..2
        const int j   = g % 12;           // instr within row
        int hh = h + row - 1;
        hh = hh < 0 ? 0 : (hh > 63 ? 63 : hh);
        const int c   = j * 64 + lane;    // chunk 0..767
        const int pix = c / 12;
        const int off = c % 12;
        const size_t gsrc = ((size_t)(rowid - h + hh) * 64 + pix) * 768 + qc0 + off * 8;
        gload_lds16(xz + gsrc, &lx[row * (64 * QCH) + j * 512]);
    }
    __syncthreads();

    const bool rv0 = (h > 0), rv2 = (h < 63);

    // --- compute: 768 items (px,cg), 3 per thread ---
    #pragma unroll
    for (int it = 0; it < 3; ++it) {
        const int f  = tid + it * 256;    // 0..767
        const int px = f / 12;
        const int cg = f % 12;
        const int c8 = cg * 8;            // channel-in-quarter base

        float acc[8];
        {
            const f32x4 ba = *reinterpret_cast<const f32x4*>(&conv_b[qc0 + c8]);
            const f32x4 bb = *reinterpret_cast<const f32x4*>(&conv_b[qc0 + c8 + 4]);
            acc[0] = ba[0]; acc[1] = ba[1]; acc[2] = ba[2]; acc[3] = ba[3];
            acc[4] = bb[0]; acc[5] = bb[1]; acc[6] = bb[2]; acc[7] = bb[3];
        }

        #pragma unroll
        for (int r = 0; r < 3; ++r) {
            if (r == 0 && !rv0) continue;
            if (r == 2 && !rv2) continue;
            const int rowb = r * (64 * QCH);
            #pragma unroll
            for (int dw = 0; dw < 3; ++dw) {
                const int col = px + dw - 1;
                if (col < 0 || col >= 64) continue;
                const short8 t = *reinterpret_cast<const short8*>(&lx[rowb + col * QCH + c8]);
                const int tap = r * 3 + dw;
                const f32x4 wa = *reinterpret_cast<const f32x4*>(&wT[tap * CIDIM + qc0 + c8]);
                const f32x4 wb = *reinterpret_cast<const f32x4*>(&wT[tap * CIDIM + qc0 + c8 + 4]);
                acc[0] += bf2f(t[0]) * wa[0]; acc[1] += bf2f(t[1]) * wa[1];
                acc[2] += bf2f(t[2]) * wa[2]; acc[3] += bf2f(t[3]) * wa[3];
                acc[4] += bf2f(t[4]) * wb[0]; acc[5] += bf2f(t[5]) * wb[1];
                acc[6] += bf2f(t[6]) * wb[2]; acc[7] += bf2f(t[7]) * wb[3];
            }
        }

        const size_t m = (size_t)rowid * 64 + px;
        const short8 zv = *reinterpret_cast<const short8*>(&xz[m * 768 + CIDIM + qc0 + c8]);
        bf16 tmp[8];
        #pragma unroll
        for (int j = 0; j < 8; ++j)
            tmp[j] = __float2bfloat16(4.0f * silu_f(acc[j]) * silu_f(bf2f(zv[j])));
        *reinterpret_cast<short8*>(&y[m * CIDIM + qc0 + c8]) =
            *reinterpret_cast<const short8*>(tmp);
    }
}

// ---------------------------------------------------------------------------
__launch_bounds__(256)
__global__ void cvt_to_bf16(const float* __restrict__ in, bf16* __restrict__ out, int n)
{
    const int i = (blockIdx.x * 256 + threadIdx.x) * 4;
    if (i < n) {
        const float4 v = *reinterpret_cast<const float4*>(&in[i]);
        out[i + 0] = __float2bfloat16(v.x);
        out[i + 1] = __float2bfloat16(v.y);
        out[i + 2] = __float2bfloat16(v.z);
        out[i + 3] = __float2bfloat16(v.w);
    }
}

// ---------------------------------------------------------------------------
// All weight preprocessing in ONE launch.
// ---------------------------------------------------------------------------
#define SZ_WIN  (192 * 768)
#define SZ_WOUT (384 * 192)
#define SZ_WM1  (192 * 768)
#define SZ_WM2  (768 * 192)
#define SZ_CW   (CIDIM * 9)
#define SZ_PREP (SZ_WIN + SZ_WOUT + SZ_WM1 + SZ_WM2 + SZ_CW)

__launch_bounds__(256)
__global__ void prep_weights(const float* __restrict__ Win, const float* __restrict__ Wout,
                             const float* __restrict__ Wm1, const float* __restrict__ Wm2,
                             const float* __restrict__ convw,
                             bf16* __restrict__ WinT, bf16* __restrict__ WoutT,
                             bf16* __restrict__ Wm1T, bf16* __restrict__ Wm2T,
                             float* __restrict__ wTc)
{
    int idx = blockIdx.x * 256 + threadIdx.x;
    if (idx < SZ_WIN) {
        const int r = idx / 768, c = idx % 768;
        WinT[(size_t)c * 192 + r] = __float2bfloat16(Win[idx]);
        return;
    }
    idx -= SZ_WIN;
    if (idx < SZ_WOUT) {
        const int r = idx / 192, c = idx % 192;
        WoutT[(size_t)c * 384 + r] = __float2bfloat16(Wout[idx]);
        return;
    }
    idx -= SZ_WOUT;
    if (idx < SZ_WM1) {
        const int r = idx / 768, c = idx % 768;
        Wm1T[(size_t)c * 192 + r] = __float2bfloat16(Wm1[idx]);
        return;
    }
    idx -= SZ_WM1;
    if (idx < SZ_WM2) {
        const int r = idx / 192, c = idx % 192;
        Wm2T[(size_t)c * 768 + r] = __float2bfloat16(Wm2[idx]);
        return;
    }
    idx -= SZ_WM2;
    if (idx < SZ_CW) {
        const int ci = idx / 9, t = idx % 9;
        wTc[t * CIDIM + ci] = convw[idx];
    }
}

// ---------------------------------------------------------------------------
extern "C" void kernel_launch(void* const* d_in, const int* in_sizes, int n_in,
                              void* d_out, int out_size, void* d_ws, size_t ws_size,
                              hipStream_t stream)
{
    const float* x      = (const float*)d_in[0];
    const float* Win    = (const float*)d_in[1];
    const float* conv_w = (const float*)d_in[2];
    const float* conv_b = (const float*)d_in[3];
    const float* Wout   = (const float*)d_in[4];
    const float* Wm1    = (const float*)d_in[5];
    const float* bm1    = (const float*)d_in[6];
    const float* Wm2    = (const float*)d_in[7];
    const float* bm2    = (const float*)d_in[8];
    float* out = (float*)d_out;

    char* ws = (char*)d_ws;
    size_t o = 0;
    bf16*  xb    = (bf16*)(ws + o); o += (size_t)MTOK * CDIM * 2;
    bf16*  WinT  = (bf16*)(ws + o); o += (size_t)768 * 192 * 2;
    bf16*  WoutT = (bf16*)(ws + o); o += (size_t)192 * 384 * 2;
    bf16*  Wm1T  = (bf16*)(ws + o); o += (size_t)768 * 192 * 2;
    bf16*  Wm2T  = (bf16*)(ws + o); o += (size_t)192 * 768 * 2;
    float* wTc   = (float*)(ws + o); o += (size_t)9 * CIDIM * 4;
    bf16*  ws_xz = (bf16*)(ws + o); o += (size_t)MTOK * 768 * 2;
    bf16*  ws_y  = (bf16*)(ws + o); o += (size_t)MTOK * CIDIM * 2;
    bf16*  ws_ob = (bf16*)(ws + o); o += (size_t)MTOK * CDIM * 2;
    bf16*  ws_h  = ws_xz;

    {
        const int n = MTOK * CDIM;
        cvt_to_bf16<<<dim3(n / 4 / 256), dim3(256), 0, stream>>>(x, xb, n);
        prep_weights<<<dim3((SZ_PREP + 255) / 256), dim3(256), 0, stream>>>(
            Win, Wout, Wm1, Wm2, conv_w, WinT, WoutT, Wm1T, Wm2T, wTc);
    }

    // 1) xz = x @ Win   [M,768], K=192 -> bf16
    gemm_mfma<0><<<dim3(768 / 64, MTOK / 128), dim3(256), 0, stream>>>(
        xb, WinT, nullptr, nullptr, nullptr, ws_xz, MTOK, 768, CDIM);

    // 2) y = 4*silu(dwconv(x1)+b) * silu(z) -> bf16
    dwconv_gate_v5<<<dim3(512 * 4), dim3(256), 0, stream>>>(ws_xz, wTc, conv_b, ws_y);

    // 3) out = x + y @ Wout   [M,192], K=384 -> fp32 + bf16
    gemm_mfma<1><<<dim3(192 / 64, MTOK / 128), dim3(256), 0, stream>>>(
        ws_y, WoutT, nullptr, x, out, ws_ob, MTOK, CDIM, CIDIM);

    // 4) h = silu(out @ Wm1 + bm1)   [M,768], K=192 -> bf16
    gemm_mfma<2><<<dim3(768 / 64, MTOK / 128), dim3(256), 0, stream>>>(
        ws_ob, Wm1T, bm1, nullptr, nullptr, ws_h, MTOK, 768, CDIM);

    // 5) final = out + h @ Wm2 + bm2   [M,192], K=768 -> fp32 (in-place)
    gemm_mfma<3><<<dim3(192 / 64, MTOK / 128), dim3(256), 0, stream>>>(
        ws_h, Wm2T, bm2, out, out, nullptr, MTOK, CDIM, 768);
}

// Round 6
// 147.350 us; speedup vs baseline: 1.0762x; 1.0762x over previous
//
#include <hip/hip_runtime.h>
#include <hip/hip_bf16.h>

// Problem constants
#define BDIM 8
#define HDIM 64
#define WDIM 64
#define CDIM 192
#define CIDIM 384
#define MTOK (BDIM * HDIM * WDIM)   // 32768 tokens

using bf16 = __hip_bfloat16;
typedef __attribute__((ext_vector_type(8))) short short8;   // 8 bf16 (4 VGPRs)
typedef __attribute__((ext_vector_type(4))) float f32x4;

__device__ __forceinline__ float silu_f(float v) { return v / (1.0f + __expf(-v)); }
__device__ __forceinline__ float bf2f(short s) {
    union { unsigned u; float f; } x; x.u = ((unsigned)(unsigned short)s) << 16; return x.f;
}

// async global->LDS, 16B per lane. LDS dest must be WAVE-UNIFORM base (+lane*16);
// the GLOBAL source address is per-lane.
__device__ __forceinline__ void gload_lds16(const bf16* g, bf16* l) {
    __builtin_amdgcn_global_load_lds(
        (const __attribute__((address_space(1))) void*)g,
        (__attribute__((address_space(3))) void*)l, 16, 0, 0);
}

// ---------------------------------------------------------------------------
// MFMA GEMM: C[M,N] = A[M,K] @ B[K,N], A bf16 [M,K], B TRANSPOSED bf16 [N,K].
// BM=128, BN=64, BK=64. 256 threads = 4 waves 2x2; wave tile 64x32 (4x2 frags).
// LDS linear, 16B slots XOR-swizzled both-sides.
// EPI: 0 = split-store: n<384 -> outB (x1), n>=384 -> outB2 = 4*silu(v)  [sz]
//      1 = +resid -> fp32 + bf16; 2 = silu(+bias) -> bf16; 3 = +bias+resid -> fp32
// ---------------------------------------------------------------------------
template <int EPI>
__launch_bounds__(256, 4)
__global__ void gemm_mfma(const bf16* __restrict__ A, const bf16* __restrict__ BT,
                          const float* __restrict__ bias, const float* __restrict__ resid,
                          float* __restrict__ outF, bf16* __restrict__ outB,
                          bf16* __restrict__ outB2,
                          int M, int N, int K)
{
    __shared__ bf16 As[128 * 64];
    __shared__ bf16 Bs[64 * 64];

    const int tid  = threadIdx.x;
    const int lane = tid & 63;
    const int wv   = tid >> 6;
    const int wm   = wv >> 1;
    const int wn   = wv & 1;
    const int m0   = blockIdx.y * 128;
    const int n0   = blockIdx.x * 64;

    const int srow  = lane >> 3;
    const int sslot = lane & 7;

    f32x4 acc[4][2] = {};

    for (int k0 = 0; k0 < K; k0 += 64) {
        #pragma unroll
        for (int i = 0; i < 4; ++i) {
            const int rb = wv * 32 + i * 8;
            const int r  = rb + srow;
            gload_lds16(A + (size_t)(m0 + r) * K + k0 + ((sslot ^ (r & 7)) << 3),
                        &As[rb * 64]);
        }
        #pragma unroll
        for (int i = 0; i < 2; ++i) {
            const int rb = wv * 16 + i * 8;
            const int r  = rb + srow;
            gload_lds16(BT + (size_t)(n0 + r) * K + k0 + ((sslot ^ (r & 7)) << 3),
                        &Bs[rb * 64]);
        }
        __syncthreads();

        #pragma unroll
        for (int kk = 0; kk < 2; ++kk) {
            const int t = kk * 4 + (lane >> 4);
            short8 af[4], bfr[2];
            #pragma unroll
            for (int mi = 0; mi < 4; ++mi) {
                const int m = wm * 64 + mi * 16 + (lane & 15);
                af[mi] = *reinterpret_cast<const short8*>(&As[m * 64 + ((t ^ (m & 7)) << 3)]);
            }
            #pragma unroll
            for (int ni = 0; ni < 2; ++ni) {
                const int n = wn * 32 + ni * 16 + (lane & 15);
                bfr[ni] = *reinterpret_cast<const short8*>(&Bs[n * 64 + ((t ^ (n & 7)) << 3)]);
            }
            #pragma unroll
            for (int mi = 0; mi < 4; ++mi)
                #pragma unroll
                for (int ni = 0; ni < 2; ++ni)
                    acc[mi][ni] = __builtin_amdgcn_mfma_f32_16x16x32_bf16(
                        af[mi], bfr[ni], acc[mi][ni], 0, 0, 0);
        }
        __syncthreads();
    }

    const int colb = n0 + wn * 32 + (lane & 15);
    const int rowb = m0 + wm * 64 + (lane >> 4) * 4;
    #pragma unroll
    for (int mi = 0; mi < 4; ++mi) {
        #pragma unroll
        for (int ni = 0; ni < 2; ++ni) {
            const int c = colb + ni * 16;
            #pragma unroll
            for (int j = 0; j < 4; ++j) {
                const int row = rowb + mi * 16 + j;
                const float v = acc[mi][ni][j];
                if constexpr (EPI == 0) {
                    // deinterleave: x1 dense, sz = 4*silu(z) dense
                    if (c < CIDIM)
                        outB[(size_t)row * CIDIM + c] = __float2bfloat16(v);
                    else
                        outB2[(size_t)row * CIDIM + (c - CIDIM)] =
                            __float2bfloat16(4.0f * silu_f(v));
                } else if constexpr (EPI == 1) {
                    const size_t off = (size_t)row * N + c;
                    const float r = v + resid[off];
                    outF[off] = r;
                    outB[off] = __float2bfloat16(r);
                } else if constexpr (EPI == 2) {
                    const size_t off = (size_t)row * N + c;
                    outB[off] = __float2bfloat16(silu_f(v + bias[c]));
                } else {
                    const size_t off = (size_t)row * N + c;
                    outF[off] = v + bias[c] + resid[off];
                }
            }
        }
    }
}

// ---------------------------------------------------------------------------
// Depthwise 3x3 conv + bias + silu, gated.  v6: DENSE streams.
// x1 [M,384] bf16 (dense), sz [M,384] bf16 (= 4*silu(z), dense).
// Item f = m*48 + cg (8 ch): wave's 64 lanes = 1KB contiguous per tap.
// 9 taps = same dense stream shifted by ±768B / ±48KB -> L2-served re-reads.
// XCD-contiguous block swizzle keeps a row's 3 visits on one XCD's L2.
// y[m,c] = silu(conv(x1)+b) * sz.   Grid: 6144 blocks x 256 thr.
// ---------------------------------------------------------------------------
__launch_bounds__(256)
__global__ void dwconv_gate_v6(const bf16* __restrict__ x1, const bf16* __restrict__ sz,
                               const float* __restrict__ wT, const float* __restrict__ conv_b,
                               bf16* __restrict__ y)
{
    const int bid = blockIdx.x;
    const int swz = (bid & 7) * ((int)gridDim.x >> 3) + (bid >> 3);   // bijective (6144 % 8 == 0)
    const int f   = swz * 256 + threadIdx.x;
    const int m   = f / 48;
    const int cg  = f - m * 48;
    const int c0  = cg * 8;
    const int h   = (m >> 6) & 63;
    const int w   = m & 63;

    float acc[8];
    {
        const f32x4 ba = *reinterpret_cast<const f32x4*>(&conv_b[c0]);
        const f32x4 bb = *reinterpret_cast<const f32x4*>(&conv_b[c0 + 4]);
        acc[0] = ba[0]; acc[1] = ba[1]; acc[2] = ba[2]; acc[3] = ba[3];
        acc[4] = bb[0]; acc[5] = bb[1]; acc[6] = bb[2]; acc[7] = bb[3];
    }

    #pragma unroll
    for (int r = 0; r < 3; ++r) {
        const int hh = h + r - 1;
        if (hh < 0 || hh >= HDIM) continue;
        #pragma unroll
        for (int dw = 0; dw < 3; ++dw) {
            const int ww = w + dw - 1;
            if (ww < 0 || ww >= WDIM) continue;
            const int mm  = m + (r - 1) * WDIM + (dw - 1);
            const int tap = r * 3 + dw;
            const short8 t = *reinterpret_cast<const short8*>(&x1[(size_t)mm * CIDIM + c0]);
            const f32x4 wa = *reinterpret_cast<const f32x4*>(&wT[tap * CIDIM + c0]);
            const f32x4 wb = *reinterpret_cast<const f32x4*>(&wT[tap * CIDIM + c0 + 4]);
            acc[0] += bf2f(t[0]) * wa[0]; acc[1] += bf2f(t[1]) * wa[1];
            acc[2] += bf2f(t[2]) * wa[2]; acc[3] += bf2f(t[3]) * wa[3];
            acc[4] += bf2f(t[4]) * wb[0]; acc[5] += bf2f(t[5]) * wb[1];
            acc[6] += bf2f(t[6]) * wb[2]; acc[7] += bf2f(t[7]) * wb[3];
        }
    }

    const short8 g = *reinterpret_cast<const short8*>(&sz[(size_t)m * CIDIM + c0]);
    bf16 tmp[8];
    #pragma unroll
    for (int j = 0; j < 8; ++j)
        tmp[j] = __float2bfloat16(silu_f(acc[j]) * bf2f(g[j]));   // x4 pre-folded into sz
    *reinterpret_cast<short8*>(&y[(size_t)m * CIDIM + c0]) =
        *reinterpret_cast<const short8*>(tmp);
}

// ---------------------------------------------------------------------------
__launch_bounds__(256)
__global__ void cvt_to_bf16(const float* __restrict__ in, bf16* __restrict__ out, int n)
{
    const int i = (blockIdx.x * 256 + threadIdx.x) * 4;
    if (i < n) {
        const float4 v = *reinterpret_cast<const float4*>(&in[i]);
        out[i + 0] = __float2bfloat16(v.x);
        out[i + 1] = __float2bfloat16(v.y);
        out[i + 2] = __float2bfloat16(v.z);
        out[i + 3] = __float2bfloat16(v.w);
    }
}

// ---------------------------------------------------------------------------
// All weight preprocessing in ONE launch.
// ---------------------------------------------------------------------------
#define SZ_WIN  (192 * 768)
#define SZ_WOUT (384 * 192)
#define SZ_WM1  (192 * 768)
#define SZ_WM2  (768 * 192)
#define SZ_CW   (CIDIM * 9)
#define SZ_PREP (SZ_WIN + SZ_WOUT + SZ_WM1 + SZ_WM2 + SZ_CW)

__launch_bounds__(256)
__global__ void prep_weights(const float* __restrict__ Win, const float* __restrict__ Wout,
                             const float* __restrict__ Wm1, const float* __restrict__ Wm2,
                             const float* __restrict__ convw,
                             bf16* __restrict__ WinT, bf16* __restrict__ WoutT,
                             bf16* __restrict__ Wm1T, bf16* __restrict__ Wm2T,
                             float* __restrict__ wTc)
{
    int idx = blockIdx.x * 256 + threadIdx.x;
    if (idx < SZ_WIN) {
        const int r = idx / 768, c = idx % 768;
        WinT[(size_t)c * 192 + r] = __float2bfloat16(Win[idx]);
        return;
    }
    idx -= SZ_WIN;
    if (idx < SZ_WOUT) {
        const int r = idx / 192, c = idx % 192;
        WoutT[(size_t)c * 384 + r] = __float2bfloat16(Wout[idx]);
        return;
    }
    idx -= SZ_WOUT;
    if (idx < SZ_WM1) {
        const int r = idx / 768, c = idx % 768;
        Wm1T[(size_t)c * 192 + r] = __float2bfloat16(Wm1[idx]);
        return;
    }
    idx -= SZ_WM1;
    if (idx < SZ_WM2) {
        const int r = idx / 192, c = idx % 192;
        Wm2T[(size_t)c * 768 + r] = __float2bfloat16(Wm2[idx]);
        return;
    }
    idx -= SZ_WM2;
    if (idx < SZ_CW) {
        const int ci = idx / 9, t = idx % 9;
        wTc[t * CIDIM + ci] = convw[idx];
    }
}

// ---------------------------------------------------------------------------
extern "C" void kernel_launch(void* const* d_in, const int* in_sizes, int n_in,
                              void* d_out, int out_size, void* d_ws, size_t ws_size,
                              hipStream_t stream)
{
    const float* x      = (const float*)d_in[0];
    const float* Win    = (const float*)d_in[1];
    const float* conv_w = (const float*)d_in[2];
    const float* conv_b = (const float*)d_in[3];
    const float* Wout   = (const float*)d_in[4];
    const float* Wm1    = (const float*)d_in[5];
    const float* bm1    = (const float*)d_in[6];
    const float* Wm2    = (const float*)d_in[7];
    const float* bm2    = (const float*)d_in[8];
    float* out = (float*)d_out;

    char* ws = (char*)d_ws;
    size_t o = 0;
    bf16*  xb    = (bf16*)(ws + o); o += (size_t)MTOK * CDIM * 2;
    bf16*  WinT  = (bf16*)(ws + o); o += (size_t)768 * 192 * 2;
    bf16*  WoutT = (bf16*)(ws + o); o += (size_t)192 * 384 * 2;
    bf16*  Wm1T  = (bf16*)(ws + o); o += (size_t)768 * 192 * 2;
    bf16*  Wm2T  = (bf16*)(ws + o); o += (size_t)192 * 768 * 2;
    float* wTc   = (float*)(ws + o); o += (size_t)9 * CIDIM * 4;
    bf16*  ws_x1 = (bf16*)(ws + o); o += (size_t)MTOK * CIDIM * 2;   // dense x1 [M,384]
    bf16*  ws_sz = (bf16*)(ws + o); o += (size_t)MTOK * CIDIM * 2;   // dense 4*silu(z)
    bf16*  ws_y  = (bf16*)(ws + o); o += (size_t)MTOK * CIDIM * 2;
    bf16*  ws_ob = (bf16*)(ws + o); o += (size_t)MTOK * CDIM * 2;
    bf16*  ws_h  = ws_x1;   // GEMM4 output [M,768] reuses x1+sz region (dead by then)

    {
        const int n = MTOK * CDIM;
        cvt_to_bf16<<<dim3(n / 4 / 256), dim3(256), 0, stream>>>(x, xb, n);
        prep_weights<<<dim3((SZ_PREP + 255) / 256), dim3(256), 0, stream>>>(
            Win, Wout, Wm1, Wm2, conv_w, WinT, WoutT, Wm1T, Wm2T, wTc);
    }

    // 1) xz = x @ Win  [M,768], K=192 -> split dense x1 / sz(=4*silu(z))
    gemm_mfma<0><<<dim3(768 / 64, MTOK / 128), dim3(256), 0, stream>>>(
        xb, WinT, nullptr, nullptr, nullptr, ws_x1, ws_sz, MTOK, 768, CDIM);

    // 2) y = silu(dwconv(x1)+b) * sz -> bf16
    dwconv_gate_v6<<<dim3(MTOK * 48 / 256), dim3(256), 0, stream>>>(
        ws_x1, ws_sz, wTc, conv_b, ws_y);

    // 3) out = x + y @ Wout   [M,192], K=384 -> fp32 + bf16
    gemm_mfma<1><<<dim3(192 / 64, MTOK / 128), dim3(256), 0, stream>>>(
        ws_y, WoutT, nullptr, x, out, ws_ob, nullptr, MTOK, CDIM, CIDIM);

    // 4) h = silu(out @ Wm1 + bm1)   [M,768], K=192 -> bf16 (over x1/sz region)
    gemm_mfma<2><<<dim3(768 / 64, MTOK / 128), dim3(256), 0, stream>>>(
        ws_ob, Wm1T, bm1, nullptr, nullptr, ws_h, nullptr, MTOK, 768, CDIM);

    // 5) final = out + h @ Wm2 + bm2   [M,192], K=768 -> fp32 (in-place)
    gemm_mfma<3><<<dim3(192 / 64, MTOK / 128), dim3(256), 0, stream>>>(
        ws_h, Wm2T, bm2, out, out, nullptr, nullptr, MTOK, CDIM, 768);
}

// Round 8
// 141.945 us; speedup vs baseline: 1.1172x; 1.0381x over previous
//
#include <hip/hip_runtime.h>
#include <hip/hip_bf16.h>

// Problem constants
#define BDIM 8
#define HDIM 64
#define WDIM 64
#define CDIM 192
#define CIDIM 384
#define MTOK (BDIM * HDIM * WDIM)   // 32768 tokens

using bf16 = __hip_bfloat16;
typedef __attribute__((ext_vector_type(8))) short short8;   // 8 bf16 (4 VGPRs)
typedef __attribute__((ext_vector_type(4))) float f32x4;

__device__ __forceinline__ float silu_f(float v) { return v / (1.0f + __expf(-v)); }
__device__ __forceinline__ float bf2f(short s) {
    union { unsigned u; float f; } x; x.u = ((unsigned)(unsigned short)s) << 16; return x.f;
}

// async global->LDS, 16B per lane. LDS dest must be WAVE-UNIFORM base (+lane*16);
// the GLOBAL source address is per-lane.
__device__ __forceinline__ void gload_lds16(const bf16* g, bf16* l) {
    __builtin_amdgcn_global_load_lds(
        (const __attribute__((address_space(1))) void*)g,
        (__attribute__((address_space(3))) void*)l, 16, 0, 0);
}

// ---------------------------------------------------------------------------
// MFMA GEMM: C[M,N] = A[M,K] @ B[K,N], A bf16 [M,K], B TRANSPOSED bf16 [N,K].
// BM=128, BN=32*NF (NF=4 -> 128x128 m97-config; NF=2 -> 128x64).
// 256 threads = 4 waves 2x2; wave tile 64 x (16*NF); acc 4xNF f32x4 frags.
// LDS linear, 16B slots XOR-swizzled both-sides.
// EPI 0: split-store n<384 -> outB (x1), else outB2 = 4*silu(v)      [G1]
// EPI 1: +residF(fp32) -> outB bf16 only                              [G3]
// EPI 2: silu(v+bias) -> outB bf16                                    [G4]
// EPI 3: v + bias + bf2f(residB) -> outF fp32                         [G5]
// ---------------------------------------------------------------------------
template <int EPI, int NF>
__launch_bounds__(256, NF == 4 ? 2 : 4)
__global__ void gemm_mfma(const bf16* __restrict__ A, const bf16* __restrict__ BT,
                          const float* __restrict__ bias,
                          const float* __restrict__ residF,
                          const bf16* __restrict__ residB,
                          float* __restrict__ outF, bf16* __restrict__ outB,
                          bf16* __restrict__ outB2,
                          int M, int N, int K)
{
    constexpr int BN = 32 * NF;
    __shared__ bf16 As[128 * 64];
    __shared__ bf16 Bs[BN * 64];

    const int tid  = threadIdx.x;
    const int lane = tid & 63;
    const int wv   = tid >> 6;
    const int wm   = wv >> 1;
    const int wn   = wv & 1;
    const int m0   = blockIdx.y * 128;
    const int n0   = blockIdx.x * BN;

    const int srow  = lane >> 3;
    const int sslot = lane & 7;

    f32x4 acc[4][NF] = {};

    for (int k0 = 0; k0 < K; k0 += 64) {
        #pragma unroll
        for (int i = 0; i < 4; ++i) {
            const int rb = wv * 32 + i * 8;
            const int r  = rb + srow;
            gload_lds16(A + (size_t)(m0 + r) * K + k0 + ((sslot ^ (r & 7)) << 3),
                        &As[rb * 64]);
        }
        #pragma unroll
        for (int i = 0; i < NF; ++i) {
            const int rb = wv * (BN / 4) + i * 8;
            const int r  = rb + srow;
            gload_lds16(BT + (size_t)(n0 + r) * K + k0 + ((sslot ^ (r & 7)) << 3),
                        &Bs[rb * 64]);
        }
        __syncthreads();

        #pragma unroll
        for (int kk = 0; kk < 2; ++kk) {
            const int t = kk * 4 + (lane >> 4);
            short8 af[4], bfr[NF];
            #pragma unroll
            for (int mi = 0; mi < 4; ++mi) {
                const int m = wm * 64 + mi * 16 + (lane & 15);
                af[mi] = *reinterpret_cast<const short8*>(&As[m * 64 + ((t ^ (m & 7)) << 3)]);
            }
            #pragma unroll
            for (int ni = 0; ni < NF; ++ni) {
                const int n = wn * (16 * NF) + ni * 16 + (lane & 15);
                bfr[ni] = *reinterpret_cast<const short8*>(&Bs[n * 64 + ((t ^ (n & 7)) << 3)]);
            }
            #pragma unroll
            for (int mi = 0; mi < 4; ++mi)
                #pragma unroll
                for (int ni = 0; ni < NF; ++ni)
                    acc[mi][ni] = __builtin_amdgcn_mfma_f32_16x16x32_bf16(
                        af[mi], bfr[ni], acc[mi][ni], 0, 0, 0);
        }
        __syncthreads();
    }

    // C/D layout: col = lane&15, row = (lane>>4)*4 + j
    const int colb = n0 + wn * (16 * NF) + (lane & 15);
    const int rowb = m0 + wm * 64 + (lane >> 4) * 4;
    #pragma unroll
    for (int mi = 0; mi < 4; ++mi) {
        #pragma unroll
        for (int ni = 0; ni < NF; ++ni) {
            const int c = colb + ni * 16;
            #pragma unroll
            for (int j = 0; j < 4; ++j) {
                const int row = rowb + mi * 16 + j;
                const float v = acc[mi][ni][j];
                if constexpr (EPI == 0) {
                    if (c < CIDIM)
                        outB[(size_t)row * CIDIM + c] = __float2bfloat16(v);
                    else
                        outB2[(size_t)row * CIDIM + (c - CIDIM)] =
                            __float2bfloat16(4.0f * silu_f(v));
                } else if constexpr (EPI == 1) {
                    const size_t off = (size_t)row * N + c;
                    outB[off] = __float2bfloat16(v + residF[off]);
                } else if constexpr (EPI == 2) {
                    const size_t off = (size_t)row * N + c;
                    outB[off] = __float2bfloat16(silu_f(v + bias[c]));
                } else {
                    const size_t off = (size_t)row * N + c;
                    outF[off] = v + bias[c] + bf2f(*(const short*)&residB[off]);
                }
            }
        }
    }
}

// ---------------------------------------------------------------------------
// Depthwise 3x3 conv + bias + silu, gated. Dense streams:
// x1 [M,384] bf16, sz [M,384] bf16 (= 4*silu(z)). Item f = m*48 + cg.
// y[m,c] = silu(conv(x1)+b) * sz.  Grid: 6144 blocks x 256 thr, XCD-swizzled.
// ---------------------------------------------------------------------------
__launch_bounds__(256)
__global__ void dwconv_gate_v6(const bf16* __restrict__ x1, const bf16* __restrict__ sz,
                               const float* __restrict__ wT, const float* __restrict__ conv_b,
                               bf16* __restrict__ y)
{
    const int bid = blockIdx.x;
    const int swz = (bid & 7) * ((int)gridDim.x >> 3) + (bid >> 3);   // bijective (6144 % 8 == 0)
    const int f   = swz * 256 + threadIdx.x;
    const int m   = f / 48;
    const int cg  = f - m * 48;
    const int c0  = cg * 8;
    const int h   = (m >> 6) & 63;
    const int w   = m & 63;

    float acc[8];
    {
        const f32x4 ba = *reinterpret_cast<const f32x4*>(&conv_b[c0]);
        const f32x4 bb = *reinterpret_cast<const f32x4*>(&conv_b[c0 + 4]);
        acc[0] = ba[0]; acc[1] = ba[1]; acc[2] = ba[2]; acc[3] = ba[3];
        acc[4] = bb[0]; acc[5] = bb[1]; acc[6] = bb[2]; acc[7] = bb[3];
    }

    #pragma unroll
    for (int r = 0; r < 3; ++r) {
        const int hh = h + r - 1;
        if (hh < 0 || hh >= HDIM) continue;
        #pragma unroll
        for (int dw = 0; dw < 3; ++dw) {
            const int ww = w + dw - 1;
            if (ww < 0 || ww >= WDIM) continue;
            const int mm  = m + (r - 1) * WDIM + (dw - 1);
            const int tap = r * 3 + dw;
            const short8 t = *reinterpret_cast<const short8*>(&x1[(size_t)mm * CIDIM + c0]);
            const f32x4 wa = *reinterpret_cast<const f32x4*>(&wT[tap * CIDIM + c0]);
            const f32x4 wb = *reinterpret_cast<const f32x4*>(&wT[tap * CIDIM + c0 + 4]);
            acc[0] += bf2f(t[0]) * wa[0]; acc[1] += bf2f(t[1]) * wa[1];
            acc[2] += bf2f(t[2]) * wa[2]; acc[3] += bf2f(t[3]) * wa[3];
            acc[4] += bf2f(t[4]) * wb[0]; acc[5] += bf2f(t[5]) * wb[1];
            acc[6] += bf2f(t[6]) * wb[2]; acc[7] += bf2f(t[7]) * wb[3];
        }
    }

    const short8 g = *reinterpret_cast<const short8*>(&sz[(size_t)m * CIDIM + c0]);
    bf16 tmp[8];
    #pragma unroll
    for (int j = 0; j < 8; ++j)
        tmp[j] = __float2bfloat16(silu_f(acc[j]) * bf2f(g[j]));
    *reinterpret_cast<short8*>(&y[(size_t)m * CIDIM + c0]) =
        *reinterpret_cast<const short8*>(tmp);
}

// ---------------------------------------------------------------------------
// ALL preprocessing in ONE launch: x fp32->bf16 (4/thread) + 4 weight
// transposes to bf16 [N,K] + conv_w transpose, flat-index dispatched.
// ---------------------------------------------------------------------------
#define SZ_WIN  (192 * 768)
#define SZ_WOUT (384 * 192)
#define SZ_WM1  (192 * 768)
#define SZ_WM2  (768 * 192)
#define SZ_CW   (CIDIM * 9)
#define XCVT    (MTOK * CDIM / 4)
#define SZ_ALL  (XCVT + SZ_WIN + SZ_WOUT + SZ_WM1 + SZ_WM2 + SZ_CW)

__launch_bounds__(256)
__global__ void prep_all(const float* __restrict__ x, const float* __restrict__ Win,
                         const float* __restrict__ Wout, const float* __restrict__ Wm1,
                         const float* __restrict__ Wm2, const float* __restrict__ convw,
                         bf16* __restrict__ xb, bf16* __restrict__ WinT,
                         bf16* __restrict__ WoutT, bf16* __restrict__ Wm1T,
                         bf16* __restrict__ Wm2T, float* __restrict__ wTc)
{
    int idx = blockIdx.x * 256 + threadIdx.x;
    if (idx < XCVT) {
        const int i = idx * 4;
        const float4 v = *reinterpret_cast<const float4*>(&x[i]);
        xb[i + 0] = __float2bfloat16(v.x);
        xb[i + 1] = __float2bfloat16(v.y);
        xb[i + 2] = __float2bfloat16(v.z);
        xb[i + 3] = __float2bfloat16(v.w);
        return;
    }
    idx -= XCVT;
    if (idx < SZ_WIN) {
        const int r = idx / 768, c = idx % 768;
        WinT[(size_t)c * 192 + r] = __float2bfloat16(Win[idx]);
        return;
    }
    idx -= SZ_WIN;
    if (idx < SZ_WOUT) {
        const int r = idx / 192, c = idx % 192;
        WoutT[(size_t)c * 384 + r] = __float2bfloat16(Wout[idx]);
        return;
    }
    idx -= SZ_WOUT;
    if (idx < SZ_WM1) {
        const int r = idx / 768, c = idx % 768;
        Wm1T[(size_t)c * 192 + r] = __float2bfloat16(Wm1[idx]);
        return;
    }
    idx -= SZ_WM1;
    if (idx < SZ_WM2) {
        const int r = idx / 192, c = idx % 192;
        Wm2T[(size_t)c * 768 + r] = __float2bfloat16(Wm2[idx]);
        return;
    }
    idx -= SZ_WM2;
    if (idx < SZ_CW) {
        const int ci = idx / 9, t = idx % 9;
        wTc[t * CIDIM + ci] = convw[idx];
    }
}

// ---------------------------------------------------------------------------
extern "C" void kernel_launch(void* const* d_in, const int* in_sizes, int n_in,
                              void* d_out, int out_size, void* d_ws, size_t ws_size,
                              hipStream_t stream)
{
    const float* x      = (const float*)d_in[0];
    const float* Win    = (const float*)d_in[1];
    const float* conv_w = (const float*)d_in[2];
    const float* conv_b = (const float*)d_in[3];
    const float* Wout   = (const float*)d_in[4];
    const float* Wm1    = (const float*)d_in[5];
    const float* bm1    = (const float*)d_in[6];
    const float* Wm2    = (const float*)d_in[7];
    const float* bm2    = (const float*)d_in[8];
    float* out = (float*)d_out;

    char* ws = (char*)d_ws;
    size_t o = 0;
    bf16*  xb    = (bf16*)(ws + o); o += (size_t)MTOK * CDIM * 2;
    bf16*  WinT  = (bf16*)(ws + o); o += (size_t)768 * 192 * 2;
    bf16*  WoutT = (bf16*)(ws + o); o += (size_t)192 * 384 * 2;
    bf16*  Wm1T  = (bf16*)(ws + o); o += (size_t)768 * 192 * 2;
    bf16*  Wm2T  = (bf16*)(ws + o); o += (size_t)192 * 768 * 2;
    float* wTc   = (float*)(ws + o); o += (size_t)9 * CIDIM * 4;
    bf16*  ws_x1 = (bf16*)(ws + o); o += (size_t)MTOK * CIDIM * 2;   // dense x1 [M,384]
    bf16*  ws_sz = (bf16*)(ws + o); o += (size_t)MTOK * CIDIM * 2;   // dense 4*silu(z)
    bf16*  ws_y  = (bf16*)(ws + o); o += (size_t)MTOK * CIDIM * 2;
    bf16*  ws_ob = (bf16*)(ws + o); o += (size_t)MTOK * CDIM * 2;    // out bf16 [M,192]
    bf16*  ws_h  = ws_x1;   // GEMM4 output [M,768] reuses x1+sz region (dead by then)

    // 0) all conversions/transposes in one launch
    prep_all<<<dim3((SZ_ALL + 255) / 256), dim3(256), 0, stream>>>(
        x, Win, Wout, Wm1, Wm2, conv_w, xb, WinT, WoutT, Wm1T, Wm2T, wTc);

    // 1) xz = x @ Win  [M,768], K=192 -> split dense x1 / sz(=4*silu(z))   128x128 tile
    gemm_mfma<0, 4><<<dim3(768 / 128, MTOK / 128), dim3(256), 0, stream>>>(
        xb, WinT, nullptr, nullptr, nullptr, nullptr, ws_x1, ws_sz, MTOK, 768, CDIM);

    // 2) y = silu(dwconv(x1)+b) * sz -> bf16
    dwconv_gate_v6<<<dim3(MTOK * 48 / 256), dim3(256), 0, stream>>>(
        ws_x1, ws_sz, wTc, conv_b, ws_y);

    // 3) out = x + y @ Wout   [M,192], K=384 -> bf16 ob ONLY                128x64 tile
    gemm_mfma<1, 2><<<dim3(192 / 64, MTOK / 128), dim3(256), 0, stream>>>(
        ws_y, WoutT, nullptr, x, nullptr, nullptr, ws_ob, nullptr, MTOK, CDIM, CIDIM);

    // 4) h = silu(out @ Wm1 + bm1)   [M,768], K=192 -> bf16                 128x128 tile
    gemm_mfma<2, 4><<<dim3(768 / 128, MTOK / 128), dim3(256), 0, stream>>>(
        ws_ob, Wm1T, bm1, nullptr, nullptr, nullptr, ws_h, nullptr, MTOK, 768, CDIM);

    // 5) final = bf16(out) + h @ Wm2 + bm2   [M,192], K=768 -> fp32         128x64 tile
    gemm_mfma<3, 2><<<dim3(192 / 64, MTOK / 128), dim3(256), 0, stream>>>(
        ws_h, Wm2T, bm2, nullptr, ws_ob, out, nullptr, nullptr, MTOK, CDIM, 768);
}

// Round 9
// 124.068 us; speedup vs baseline: 1.2781x; 1.1441x over previous
//
#include <hip/hip_runtime.h>
#include <hip/hip_bf16.h>

// Problem constants
#define BDIM 8
#define HDIM 64
#define WDIM 64
#define CDIM 192
#define CIDIM 384
#define MTOK (BDIM * HDIM * WDIM)   // 32768 tokens

using bf16 = __hip_bfloat16;
typedef __attribute__((ext_vector_type(8))) short short8;   // 8 bf16 (4 VGPRs)
typedef __attribute__((ext_vector_type(4))) float f32x4;

__device__ __forceinline__ float silu_f(float v) { return v / (1.0f + __expf(-v)); }
__device__ __forceinline__ float bf2f(short s) {
    union { unsigned u; float f; } x; x.u = ((unsigned)(unsigned short)s) << 16; return x.f;
}

// async global->LDS, 16B per lane. LDS dest must be WAVE-UNIFORM base (+lane*16);
// the GLOBAL source address is per-lane.
__device__ __forceinline__ void gload_lds16(const bf16* g, bf16* l) {
    __builtin_amdgcn_global_load_lds(
        (const __attribute__((address_space(1))) void*)g,
        (__attribute__((address_space(3))) void*)l, 16, 0, 0);
}

// ---------------------------------------------------------------------------
// Full-K GEMM for K=192 (G1, G4): C[M,N] = A[M,192] @ B[192,N], B given
// TRANSPOSED [N,192]. BM=BN=64, ALL of K staged once in LDS (48 KB, 3 blk/CU):
// one issue -> one drain -> 24 MFMA/wave -> store. No mid-loop barriers.
// Grid 1D, XCD-bijective swizzle: bid%8 selects y%8, so each A 64-row panel
// is consumed entirely within ONE XCD's L2 (all NX n-tiles), A fetched once.
// Row = 192 bf16 = 24 x 16B slots; physical slot p holds logical p^(row&7)
// (both-sides swizzle: pre-swizzled global src + swizzled ds_read).
// EPI 0: split-store c<384 -> outB (x1), else outB2 = 4*silu(v)      [G1]
// EPI 2: silu(v+bias) -> outB bf16                                    [G4]
// ---------------------------------------------------------------------------
template <int EPI>
__launch_bounds__(256, 3)
__global__ void gemm_k192(const bf16* __restrict__ A, const bf16* __restrict__ BT,
                          const float* __restrict__ bias,
                          bf16* __restrict__ outB, bf16* __restrict__ outB2,
                          int N, int NX)
{
    __shared__ bf16 As[64 * 192];   // 24 KB
    __shared__ bf16 Bs[64 * 192];   // 24 KB

    const int bid = blockIdx.x;
    const int c8  = bid & 7;
    const int kk_ = bid >> 3;
    const int bx  = kk_ % NX;
    const int by  = (kk_ / NX) * 8 + c8;   // y%8 == bid%8 -> XCD-pinned panel
    const int m0  = by * 64;
    const int n0  = bx * 64;

    const int tid  = threadIdx.x;
    const int lane = tid & 63;
    const int wv   = tid >> 6;
    const int wm   = wv >> 1;
    const int wn   = wv & 1;

    // --- stage: 24 chunks (1KB each) per matrix, 6 per wave ---
    #pragma unroll
    for (int i = 0; i < 6; ++i) {
        const int ci   = wv * 6 + i;
        const int c    = ci * 64 + lane;      // 16B-chunk index 0..1535
        const int row  = c / 24;
        const int slot = c - row * 24;        // physical slot 0..23
        const int lsl  = slot ^ (row & 7);    // logical slot fetched here
        gload_lds16(A  + (size_t)(m0 + row) * 192 + lsl * 8, &As[ci * 512]);
        gload_lds16(BT + (size_t)(n0 + row) * 192 + lsl * 8, &Bs[ci * 512]);
    }
    __syncthreads();   // single drain

    // --- compute: wave tile 32x32, 6 k-steps, 24 MFMA ---
    f32x4 acc[2][2] = {};
    #pragma unroll
    for (int ks = 0; ks < 6; ++ks) {
        const int t = ks * 4 + (lane >> 4);
        short8 af[2], bfr[2];
        #pragma unroll
        for (int mi = 0; mi < 2; ++mi) {
            const int m = wm * 32 + mi * 16 + (lane & 15);
            af[mi] = *reinterpret_cast<const short8*>(&As[m * 192 + ((t ^ (m & 7)) << 3)]);
        }
        #pragma unroll
        for (int ni = 0; ni < 2; ++ni) {
            const int n = wn * 32 + ni * 16 + (lane & 15);
            bfr[ni] = *reinterpret_cast<const short8*>(&Bs[n * 192 + ((t ^ (n & 7)) << 3)]);
        }
        #pragma unroll
        for (int mi = 0; mi < 2; ++mi)
            #pragma unroll
            for (int ni = 0; ni < 2; ++ni)
                acc[mi][ni] = __builtin_amdgcn_mfma_f32_16x16x32_bf16(
                    af[mi], bfr[ni], acc[mi][ni], 0, 0, 0);
    }

    // --- epilogue: C/D layout col = lane&15, row = (lane>>4)*4 + j ---
    const int colb = n0 + wn * 32 + (lane & 15);
    const int rowb = m0 + wm * 32 + (lane >> 4) * 4;
    #pragma unroll
    for (int mi = 0; mi < 2; ++mi) {
        #pragma unroll
        for (int ni = 0; ni < 2; ++ni) {
            const int c = colb + ni * 16;
            #pragma unroll
            for (int j = 0; j < 4; ++j) {
                const int row = rowb + mi * 16 + j;
                const float v = acc[mi][ni][j];
                if constexpr (EPI == 0) {
                    if (c < CIDIM)
                        outB[(size_t)row * CIDIM + c] = __float2bfloat16(v);
                    else
                        outB2[(size_t)row * CIDIM + (c - CIDIM)] =
                            __float2bfloat16(4.0f * silu_f(v));
                } else {
                    outB[(size_t)row * N + c] = __float2bfloat16(silu_f(v + bias[c]));
                }
            }
        }
    }
}

// ---------------------------------------------------------------------------
// Loop GEMM (K=384/768): BM=128, BN=64, BK=64. 4 waves 2x2; wave 64x32.
// 1D grid + XCD-bijective swizzle (y%8 == bid%8).
// EPI 1: +residF(fp32) -> outB bf16 only                              [G3]
// EPI 3: v + bias + bf2f(residB) -> outF fp32                         [G5]
// ---------------------------------------------------------------------------
template <int EPI>
__launch_bounds__(256, 4)
__global__ void gemm_mfma(const bf16* __restrict__ A, const bf16* __restrict__ BT,
                          const float* __restrict__ bias,
                          const float* __restrict__ residF,
                          const bf16* __restrict__ residB,
                          float* __restrict__ outF, bf16* __restrict__ outB,
                          int M, int N, int K, int NX)
{
    __shared__ bf16 As[128 * 64];
    __shared__ bf16 Bs[64 * 64];

    const int bid = blockIdx.x;
    const int c8  = bid & 7;
    const int kq  = bid >> 3;
    const int bx  = kq % NX;
    const int by  = (kq / NX) * 8 + c8;
    const int m0  = by * 128;
    const int n0  = bx * 64;

    const int tid  = threadIdx.x;
    const int lane = tid & 63;
    const int wv   = tid >> 6;
    const int wm   = wv >> 1;
    const int wn   = wv & 1;

    const int srow  = lane >> 3;
    const int sslot = lane & 7;

    f32x4 acc[4][2] = {};

    for (int k0 = 0; k0 < K; k0 += 64) {
        #pragma unroll
        for (int i = 0; i < 4; ++i) {
            const int rb = wv * 32 + i * 8;
            const int r  = rb + srow;
            gload_lds16(A + (size_t)(m0 + r) * K + k0 + ((sslot ^ (r & 7)) << 3),
                        &As[rb * 64]);
        }
        #pragma unroll
        for (int i = 0; i < 2; ++i) {
            const int rb = wv * 16 + i * 8;
            const int r  = rb + srow;
            gload_lds16(BT + (size_t)(n0 + r) * K + k0 + ((sslot ^ (r & 7)) << 3),
                        &Bs[rb * 64]);
        }
        __syncthreads();

        #pragma unroll
        for (int kk = 0; kk < 2; ++kk) {
            const int t = kk * 4 + (lane >> 4);
            short8 af[4], bfr[2];
            #pragma unroll
            for (int mi = 0; mi < 4; ++mi) {
                const int m = wm * 64 + mi * 16 + (lane & 15);
                af[mi] = *reinterpret_cast<const short8*>(&As[m * 64 + ((t ^ (m & 7)) << 3)]);
            }
            #pragma unroll
            for (int ni = 0; ni < 2; ++ni) {
                const int n = wn * 32 + ni * 16 + (lane & 15);
                bfr[ni] = *reinterpret_cast<const short8*>(&Bs[n * 64 + ((t ^ (n & 7)) << 3)]);
            }
            #pragma unroll
            for (int mi = 0; mi < 4; ++mi)
                #pragma unroll
                for (int ni = 0; ni < 2; ++ni)
                    acc[mi][ni] = __builtin_amdgcn_mfma_f32_16x16x32_bf16(
                        af[mi], bfr[ni], acc[mi][ni], 0, 0, 0);
        }
        __syncthreads();
    }

    const int colb = n0 + wn * 32 + (lane & 15);
    const int rowb = m0 + wm * 64 + (lane >> 4) * 4;
    #pragma unroll
    for (int mi = 0; mi < 4; ++mi) {
        #pragma unroll
        for (int ni = 0; ni < 2; ++ni) {
            const int c = colb + ni * 16;
            #pragma unroll
            for (int j = 0; j < 4; ++j) {
                const int row = rowb + mi * 16 + j;
                const size_t off = (size_t)row * N + c;
                const float v = acc[mi][ni][j];
                if constexpr (EPI == 1) {
                    outB[off] = __float2bfloat16(v + residF[off]);
                } else {
                    outF[off] = v + bias[c] + bf2f(*(const short*)&residB[off]);
                }
            }
        }
    }
}

// ---------------------------------------------------------------------------
// Depthwise 3x3 conv + bias + silu, gated. Dense streams:
// x1 [M,384] bf16, sz [M,384] bf16 (= 4*silu(z)). Item f = m*48 + cg.
// y[m,c] = silu(conv(x1)+b) * sz.  Grid: 6144 blocks x 256 thr, XCD-swizzled.
// ---------------------------------------------------------------------------
__launch_bounds__(256)
__global__ void dwconv_gate_v6(const bf16* __restrict__ x1, const bf16* __restrict__ sz,
                               const float* __restrict__ wT, const float* __restrict__ conv_b,
                               bf16* __restrict__ y)
{
    const int bid = blockIdx.x;
    const int swz = (bid & 7) * ((int)gridDim.x >> 3) + (bid >> 3);   // bijective (6144 % 8 == 0)
    const int f   = swz * 256 + threadIdx.x;
    const int m   = f / 48;
    const int cg  = f - m * 48;
    const int c0  = cg * 8;
    const int h   = (m >> 6) & 63;
    const int w   = m & 63;

    float acc[8];
    {
        const f32x4 ba = *reinterpret_cast<const f32x4*>(&conv_b[c0]);
        const f32x4 bb = *reinterpret_cast<const f32x4*>(&conv_b[c0 + 4]);
        acc[0] = ba[0]; acc[1] = ba[1]; acc[2] = ba[2]; acc[3] = ba[3];
        acc[4] = bb[0]; acc[5] = bb[1]; acc[6] = bb[2]; acc[7] = bb[3];
    }

    #pragma unroll
    for (int r = 0; r < 3; ++r) {
        const int hh = h + r - 1;
        if (hh < 0 || hh >= HDIM) continue;
        #pragma unroll
        for (int dw = 0; dw < 3; ++dw) {
            const int ww = w + dw - 1;
            if (ww < 0 || ww >= WDIM) continue;
            const int mm  = m + (r - 1) * WDIM + (dw - 1);
            const int tap = r * 3 + dw;
            const short8 t = *reinterpret_cast<const short8*>(&x1[(size_t)mm * CIDIM + c0]);
            const f32x4 wa = *reinterpret_cast<const f32x4*>(&wT[tap * CIDIM + c0]);
            const f32x4 wb = *reinterpret_cast<const f32x4*>(&wT[tap * CIDIM + c0 + 4]);
            acc[0] += bf2f(t[0]) * wa[0]; acc[1] += bf2f(t[1]) * wa[1];
            acc[2] += bf2f(t[2]) * wa[2]; acc[3] += bf2f(t[3]) * wa[3];
            acc[4] += bf2f(t[4]) * wb[0]; acc[5] += bf2f(t[5]) * wb[1];
            acc[6] += bf2f(t[6]) * wb[2]; acc[7] += bf2f(t[7]) * wb[3];
        }
    }

    const short8 g = *reinterpret_cast<const short8*>(&sz[(size_t)m * CIDIM + c0]);
    bf16 tmp[8];
    #pragma unroll
    for (int j = 0; j < 8; ++j)
        tmp[j] = __float2bfloat16(silu_f(acc[j]) * bf2f(g[j]));
    *reinterpret_cast<short8*>(&y[(size_t)m * CIDIM + c0]) =
        *reinterpret_cast<const short8*>(tmp);
}

// ---------------------------------------------------------------------------
// ALL preprocessing in ONE launch: x fp32->bf16 (4/thread) + 4 weight
// transposes to bf16 [N,K] + conv_w transpose, flat-index dispatched.
// ---------------------------------------------------------------------------
#define SZ_WIN  (192 * 768)
#define SZ_WOUT (384 * 192)
#define SZ_WM1  (192 * 768)
#define SZ_WM2  (768 * 192)
#define SZ_CW   (CIDIM * 9)
#define XCVT    (MTOK * CDIM / 4)
#define SZ_ALL  (XCVT + SZ_WIN + SZ_WOUT + SZ_WM1 + SZ_WM2 + SZ_CW)

__launch_bounds__(256)
__global__ void prep_all(const float* __restrict__ x, const float* __restrict__ Win,
                         const float* __restrict__ Wout, const float* __restrict__ Wm1,
                         const float* __restrict__ Wm2, const float* __restrict__ convw,
                         bf16* __restrict__ xb, bf16* __restrict__ WinT,
                         bf16* __restrict__ WoutT, bf16* __restrict__ Wm1T,
                         bf16* __restrict__ Wm2T, float* __restrict__ wTc)
{
    int idx = blockIdx.x * 256 + threadIdx.x;
    if (idx < XCVT) {
        const int i = idx * 4;
        const float4 v = *reinterpret_cast<const float4*>(&x[i]);
        xb[i + 0] = __float2bfloat16(v.x);
        xb[i + 1] = __float2bfloat16(v.y);
        xb[i + 2] = __float2bfloat16(v.z);
        xb[i + 3] = __float2bfloat16(v.w);
        return;
    }
    idx -= XCVT;
    if (idx < SZ_WIN) {
        const int r = idx / 768, c = idx % 768;
        WinT[(size_t)c * 192 + r] = __float2bfloat16(Win[idx]);
        return;
    }
    idx -= SZ_WIN;
    if (idx < SZ_WOUT) {
        const int r = idx / 192, c = idx % 192;
        WoutT[(size_t)c * 384 + r] = __float2bfloat16(Wout[idx]);
        return;
    }
    idx -= SZ_WOUT;
    if (idx < SZ_WM1) {
        const int r = idx / 768, c = idx % 768;
        Wm1T[(size_t)c * 192 + r] = __float2bfloat16(Wm1[idx]);
        return;
    }
    idx -= SZ_WM1;
    if (idx < SZ_WM2) {
        const int r = idx / 192, c = idx % 192;
        Wm2T[(size_t)c * 768 + r] = __float2bfloat16(Wm2[idx]);
        return;
    }
    idx -= SZ_WM2;
    if (idx < SZ_CW) {
        const int ci = idx / 9, t = idx % 9;
        wTc[t * CIDIM + ci] = convw[idx];
    }
}

// ---------------------------------------------------------------------------
extern "C" void kernel_launch(void* const* d_in, const int* in_sizes, int n_in,
                              void* d_out, int out_size, void* d_ws, size_t ws_size,
                              hipStream_t stream)
{
    const float* x      = (const float*)d_in[0];
    const float* Win    = (const float*)d_in[1];
    const float* conv_w = (const float*)d_in[2];
    const float* conv_b = (const float*)d_in[3];
    const float* Wout   = (const float*)d_in[4];
    const float* Wm1    = (const float*)d_in[5];
    const float* bm1    = (const float*)d_in[6];
    const float* Wm2    = (const float*)d_in[7];
    const float* bm2    = (const float*)d_in[8];
    float* out = (float*)d_out;

    char* ws = (char*)d_ws;
    size_t o = 0;
    bf16*  xb    = (bf16*)(ws + o); o += (size_t)MTOK * CDIM * 2;
    bf16*  WinT  = (bf16*)(ws + o); o += (size_t)768 * 192 * 2;
    bf16*  WoutT = (bf16*)(ws + o); o += (size_t)192 * 384 * 2;
    bf16*  Wm1T  = (bf16*)(ws + o); o += (size_t)768 * 192 * 2;
    bf16*  Wm2T  = (bf16*)(ws + o); o += (size_t)192 * 768 * 2;
    float* wTc   = (float*)(ws + o); o += (size_t)9 * CIDIM * 4;
    bf16*  ws_x1 = (bf16*)(ws + o); o += (size_t)MTOK * CIDIM * 2;   // dense x1 [M,384]
    bf16*  ws_sz = (bf16*)(ws + o); o += (size_t)MTOK * CIDIM * 2;   // dense 4*silu(z)
    bf16*  ws_y  = (bf16*)(ws + o); o += (size_t)MTOK * CIDIM * 2;
    bf16*  ws_ob = (bf16*)(ws + o); o += (size_t)MTOK * CDIM * 2;    // out bf16 [M,192]
    bf16*  ws_h  = ws_x1;   // GEMM4 output [M,768] reuses x1+sz region (dead by then)

    // 0) all conversions/transposes in one launch
    prep_all<<<dim3((SZ_ALL + 255) / 256), dim3(256), 0, stream>>>(
        x, Win, Wout, Wm1, Wm2, conv_w, xb, WinT, WoutT, Wm1T, Wm2T, wTc);

    // 1) xz = x @ Win  [M,768], K=192 -> split dense x1 / sz(=4*silu(z))
    //    full-K single-stage, 64x64 tiles, XCD-pinned A panels
    gemm_k192<0><<<dim3(12 * 512), dim3(256), 0, stream>>>(
        xb, WinT, nullptr, ws_x1, ws_sz, 768, 12);

    // 2) y = silu(dwconv(x1)+b) * sz -> bf16
    dwconv_gate_v6<<<dim3(MTOK * 48 / 256), dim3(256), 0, stream>>>(
        ws_x1, ws_sz, wTc, conv_b, ws_y);

    // 3) out = x + y @ Wout   [M,192], K=384 -> bf16 ob ONLY
    gemm_mfma<1><<<dim3(3 * 256), dim3(256), 0, stream>>>(
        ws_y, WoutT, nullptr, x, nullptr, nullptr, ws_ob, MTOK, CDIM, CIDIM, 3);

    // 4) h = silu(out @ Wm1 + bm1)   [M,768], K=192 -> bf16 (full-K kernel)
    gemm_k192<2><<<dim3(12 * 512), dim3(256), 0, stream>>>(
        ws_ob, Wm1T, bm1, ws_h, nullptr, 768, 12);

    // 5) final = bf16(out) + h @ Wm2 + bm2   [M,192], K=768 -> fp32
    gemm_mfma<3><<<dim3(3 * 256), dim3(256), 0, stream>>>(
        ws_h, Wm2T, bm2, nullptr, ws_ob, out, nullptr, MTOK, CDIM, 768, 3);
}